// Round 15
// baseline (497.068 us; speedup 1.0000x reference)
//
#include <hip/hip_runtime.h>
#include <hip/hip_bf16.h>

#define VOCAB     64
#define D_MODEL   512
#define N_STATE   32
#define H_HEADS   16
#define LAYERS    4
#define D_INNER   1024
#define P_HEAD    64
#define CONV_DIM  1088
#define K_CONV    4
#define D_IN_PROJ 2128
#define NPAD_IN   2176          // 17*128
#define NPAD_HEAD 128
#define BATCH     4
#define SEQ       1024
#define NTOK      (BATCH*SEQ)
#define EPS       1e-5f
#define CL        64            // scan chunk length
#define NC        (SEQ/CL)      // 16 chunks
#define PSTR      80            // padded t-stride (bf16) for transposed LDS tiles

typedef __bf16 bf16x8 __attribute__((ext_vector_type(8)));
typedef __bf16 bf16x4 __attribute__((ext_vector_type(4)));
typedef float  f32x4  __attribute__((ext_vector_type(4)));

__device__ __forceinline__ float sigmoidf_(float x) { return 1.f / (1.f + __expf(-x)); }
__device__ __forceinline__ float softplusf_(float x) { return (x > 20.f) ? x : log1pf(__expf(x)); }

// ---------------- rmsnorm over D_MODEL=512, bf16 out; layer0 fuses embed ----------------
__global__ void rmsnorm512_kernel(const float* __restrict__ x, const float* __restrict__ w,
                                  __bf16* __restrict__ out,
                                  const int* __restrict__ tok, const float* __restrict__ emb,
                                  float* __restrict__ hout) {
  int tokid = blockIdx.x;
  int tid = threadIdx.x;
  float v0, v1;
  if (tok) {
    const float* er = emb + (size_t)tok[tokid] * D_MODEL;
    v0 = er[tid]; v1 = er[tid + 256];
    float* hr = hout + (size_t)tokid * D_MODEL;
    hr[tid] = v0; hr[tid + 256] = v1;
  } else {
    const float* xr = x + (size_t)tokid * D_MODEL;
    v0 = xr[tid]; v1 = xr[tid + 256];
  }
  float ss = v0 * v0 + v1 * v1;
  #pragma unroll
  for (int o = 32; o >= 1; o >>= 1) ss += __shfl_xor(ss, o);
  __shared__ float red[4];
  if ((tid & 63) == 0) red[tid >> 6] = ss;
  __syncthreads();
  float tot = red[0] + red[1] + red[2] + red[3];
  float sc = rsqrtf(tot * (1.f / D_MODEL) + EPS);
  out[(size_t)tokid * D_MODEL + tid]       = (__bf16)(v0 * sc * w[tid]);
  out[(size_t)tokid * D_MODEL + tid + 256] = (__bf16)(v1 * sc * w[tid + 256]);
}

// ---- batched weight transpose+cast: W[z][K][N] f32 -> Wt[z][Npad][K] bf16 ----
__global__ void transpose_cast_kernel(const float* __restrict__ W, __bf16* __restrict__ Wt,
                                      int K, int N, int Npad) {
  W  += (size_t)blockIdx.z * K * N;
  Wt += (size_t)blockIdx.z * Npad * K;
  __shared__ float T[32][33];
  int n0 = blockIdx.x * 32, k0 = blockIdx.y * 32;
  int tx = threadIdx.x & 31, ty = threadIdx.x >> 5;  // ty 0..7
  #pragma unroll
  for (int i = 0; i < 4; i++) {
    int n = n0 + tx;
    T[ty + i * 8][tx] = (n < N) ? W[(size_t)(k0 + ty + i * 8) * N + n] : 0.f;
  }
  __syncthreads();
  #pragma unroll
  for (int i = 0; i < 4; i++)
    Wt[(size_t)(n0 + ty + i * 8) * K + k0 + tx] = (__bf16)T[tx][ty + i * 8];
}

// ---------------- bf16 MFMA GEMM, 64x128 tile (out_proj / head) ----------------
#define TM 64
#define TN 128
#define TK 64
__global__ __launch_bounds__(256) void gemm_bf16_kernel(
    const __bf16* __restrict__ A, const __bf16* __restrict__ Bt,
    const float* __restrict__ bias, const float* __restrict__ res,
    float* __restrict__ C, __bf16* __restrict__ Cbf, int K, int N, int ldc) {
  __shared__ __bf16 As[TM * TK];
  __shared__ __bf16 Bs[TN * TK];
  int tid = threadIdx.x;
  int lane = tid & 63, wave = tid >> 6;
  int wm = wave >> 1, wn = wave & 1;
  int q = lane >> 4, l16 = lane & 15;
  size_t row0 = (size_t)blockIdx.y * TM;
  int col0 = blockIdx.x * TN;
  const __bf16* Ab = A + row0 * K;
  const __bf16* Bb = Bt + (size_t)col0 * K;

  bf16x8 pa[2], pb[4];
  #pragma unroll
  for (int r = 0; r < 2; r++) {
    int lin = r * 256 + tid;
    pa[r] = *(const bf16x8*)(Ab + (size_t)(lin >> 3) * K + (lin & 7) * 8);
  }
  #pragma unroll
  for (int r = 0; r < 4; r++) {
    int lin = r * 256 + tid;
    pb[r] = *(const bf16x8*)(Bb + (size_t)(lin >> 3) * K + (lin & 7) * 8);
  }

  f32x4 acc[2][4];
  #pragma unroll
  for (int i = 0; i < 2; i++)
    #pragma unroll
    for (int j = 0; j < 4; j++) acc[i][j] = (f32x4){0.f, 0.f, 0.f, 0.f};

  for (int k0 = 0; k0 < K; k0 += TK) {
    #pragma unroll
    for (int r = 0; r < 2; r++) { int lin = r * 256 + tid; *(bf16x8*)(As + lin * 8) = pa[r]; }
    #pragma unroll
    for (int r = 0; r < 4; r++) { int lin = r * 256 + tid; *(bf16x8*)(Bs + lin * 8) = pb[r]; }
    __syncthreads();
    int kn = k0 + TK;
    if (kn < K) {
      #pragma unroll
      for (int r = 0; r < 2; r++) {
        int lin = r * 256 + tid;
        pa[r] = *(const bf16x8*)(Ab + (size_t)(lin >> 3) * K + kn + (lin & 7) * 8);
      }
      #pragma unroll
      for (int r = 0; r < 4; r++) {
        int lin = r * 256 + tid;
        pb[r] = *(const bf16x8*)(Bb + (size_t)(lin >> 3) * K + kn + (lin & 7) * 8);
      }
    }
    #pragma unroll
    for (int ks = 0; ks < 2; ks++) {
      bf16x8 af[2], bfv[4];
      #pragma unroll
      for (int i = 0; i < 2; i++)
        af[i] = *(const bf16x8*)(As + (wm * 32 + i * 16 + l16) * TK + ks * 32 + q * 8);
      #pragma unroll
      for (int j = 0; j < 4; j++)
        bfv[j] = *(const bf16x8*)(Bs + (wn * 64 + j * 16 + l16) * TK + ks * 32 + q * 8);
      #pragma unroll
      for (int i = 0; i < 2; i++)
        #pragma unroll
        for (int j = 0; j < 4; j++)
          acc[i][j] = __builtin_amdgcn_mfma_f32_16x16x32_bf16(af[i], bfv[j], acc[i][j], 0, 0, 0);
    }
    __syncthreads();
  }

  #pragma unroll
  for (int i = 0; i < 2; i++) {
    size_t mrow = row0 + wm * 32 + i * 16 + q * 4;
    #pragma unroll
    for (int j = 0; j < 4; j++) {
      int col = col0 + wn * 64 + j * 16 + l16;
      if (col < N) {
        float bv = bias ? bias[col] : 0.f;
        #pragma unroll
        for (int rr = 0; rr < 4; rr++) {
          size_t off = (mrow + rr) * (size_t)ldc + col;
          float v = acc[i][j][rr] + bv;
          if (res) v += res[off];
          if (C)   C[off] = v;
          if (Cbf) Cbf[off] = (__bf16)v;
        }
      }
    }
  }
}

// ---------------- bf16 MFMA GEMM, 128x128 tile (in_proj) ----------------
__global__ __launch_bounds__(256) void gemm_bf16_128(
    const __bf16* __restrict__ A, const __bf16* __restrict__ Bt,
    const float* __restrict__ bias, __bf16* __restrict__ Cbf,
    int K, int N, int ldc) {
  __shared__ __bf16 As[128 * TK];
  __shared__ __bf16 Bs[128 * TK];
  int tid = threadIdx.x;
  int lane = tid & 63, wave = tid >> 6;
  int wm = wave >> 1, wn = wave & 1;
  int q = lane >> 4, l16 = lane & 15;
  size_t row0 = (size_t)blockIdx.y * 128;
  int col0 = blockIdx.x * 128;
  const __bf16* Ab = A + row0 * K;
  const __bf16* Bb = Bt + (size_t)col0 * K;

  bf16x8 pa[4], pb[4];
  #pragma unroll
  for (int r = 0; r < 4; r++) {
    int lin = r * 256 + tid;
    pa[r] = *(const bf16x8*)(Ab + (size_t)(lin >> 3) * K + (lin & 7) * 8);
    pb[r] = *(const bf16x8*)(Bb + (size_t)(lin >> 3) * K + (lin & 7) * 8);
  }

  f32x4 acc[4][4];
  #pragma unroll
  for (int i = 0; i < 4; i++)
    #pragma unroll
    for (int j = 0; j < 4; j++) acc[i][j] = (f32x4){0.f, 0.f, 0.f, 0.f};

  for (int k0 = 0; k0 < K; k0 += TK) {
    #pragma unroll
    for (int r = 0; r < 4; r++) {
      int lin = r * 256 + tid;
      *(bf16x8*)(As + lin * 8) = pa[r];
      *(bf16x8*)(Bs + lin * 8) = pb[r];
    }
    __syncthreads();
    int kn = k0 + TK;
    if (kn < K) {
      #pragma unroll
      for (int r = 0; r < 4; r++) {
        int lin = r * 256 + tid;
        pa[r] = *(const bf16x8*)(Ab + (size_t)(lin >> 3) * K + kn + (lin & 7) * 8);
        pb[r] = *(const bf16x8*)(Bb + (size_t)(lin >> 3) * K + kn + (lin & 7) * 8);
      }
    }
    #pragma unroll
    for (int ks = 0; ks < 2; ks++) {
      bf16x8 af[4], bfv[4];
      #pragma unroll
      for (int i = 0; i < 4; i++)
        af[i] = *(const bf16x8*)(As + (wm * 64 + i * 16 + l16) * TK + ks * 32 + q * 8);
      #pragma unroll
      for (int j = 0; j < 4; j++)
        bfv[j] = *(const bf16x8*)(Bs + (wn * 64 + j * 16 + l16) * TK + ks * 32 + q * 8);
      #pragma unroll
      for (int i = 0; i < 4; i++)
        #pragma unroll
        for (int j = 0; j < 4; j++)
          acc[i][j] = __builtin_amdgcn_mfma_f32_16x16x32_bf16(af[i], bfv[j], acc[i][j], 0, 0, 0);
    }
    __syncthreads();
  }

  #pragma unroll
  for (int i = 0; i < 4; i++) {
    size_t mrow = row0 + wm * 64 + i * 16 + q * 4;
    #pragma unroll
    for (int j = 0; j < 4; j++) {
      int col = col0 + wn * 64 + j * 16 + l16;
      if (col < N) {
        float bv = bias[col];
        #pragma unroll
        for (int rr = 0; rr < 4; rr++)
          Cbf[(mrow + rr) * (size_t)ldc + col] = (__bf16)(acc[i][j][rr] + bv);
      }
    }
  }
}

// ================= MFMA chunked SSD =================
// zxbf row: [z 0..1024 | x 1024..2048 | B 2048..2080 | C 2080..2112 | dt 2112..2128]
__device__ __forceinline__ void wave0_dt_cumsum(
    const __bf16* __restrict__ zxbf, const float* __restrict__ dt_bias,
    int b, int h, int t0, int tid, float* ldt, float* lcs) {
  if (tid < 64) {
    float dv = (float)zxbf[((size_t)(b * SEQ + t0 + tid)) * D_IN_PROJ + 2 * D_INNER + 2 * N_STATE + h]
               + dt_bias[h];
    float dtv = softplusf_(dv);
    float cs = dtv;
    #pragma unroll
    for (int off = 1; off < 64; off <<= 1) {
      float o = __shfl_up(cs, off);
      if (tid >= off) cs += o;
    }
    ldt[tid] = dtv;
    lcs[tid] = cs;
  }
}

__global__ __launch_bounds__(256) void ssd_local_kernel(
    const __bf16* __restrict__ zxbf, const float* __restrict__ conv_w,
    const float* __restrict__ conv_b, const float* __restrict__ dt_bias,
    const float* __restrict__ A_log,
    float* __restrict__ Slocal, float* __restrict__ dAprod) {
  int blk = blockIdx.x;
  int c = blk % NC;
  int h = (blk / NC) % H_HEADS;
  int b = blk / (NC * H_HEADS);
  int tid = threadIdx.x;
  int lane = tid & 63, wave = tid >> 6;
  int q = lane >> 4, l16 = lane & 15;
  int t0 = c * CL;
  float A = -__expf(A_log[h]);
  __shared__ __bf16 rawx[68][64];
  __shared__ __bf16 rawB[68][32];
  __shared__ __bf16 lxT[64][PSTR];
  __shared__ __bf16 lBT[32][PSTR];
  __shared__ float ldt[64], lcs[64];
  for (int i = tid; i < 68 * 8; i += 256) {
    int r = i >> 3, c0 = (i & 7) * 8;
    int gr = t0 - 3 + r;
    bf16x8 v;
    #pragma unroll
    for (int k = 0; k < 8; k++) v[k] = (__bf16)0.f;
    if (gr >= 0)
      v = *(const bf16x8*)(zxbf + ((size_t)(b * SEQ + gr)) * D_IN_PROJ + D_INNER + h * 64 + c0);
    *(bf16x8*)(&rawx[r][c0]) = v;
  }
  for (int i = tid; i < 68 * 4; i += 256) {
    int r = i >> 2, c0 = (i & 3) * 8;
    int gr = t0 - 3 + r;
    bf16x8 v;
    #pragma unroll
    for (int k = 0; k < 8; k++) v[k] = (__bf16)0.f;
    if (gr >= 0)
      v = *(const bf16x8*)(zxbf + ((size_t)(b * SEQ + gr)) * D_IN_PROJ + 2 * D_INNER + c0);
    *(bf16x8*)(&rawB[r][c0]) = v;
  }
  wave0_dt_cumsum(zxbf, dt_bias, b, h, t0, tid, ldt, lcs);
  __syncthreads();
  float cs63 = lcs[63];
  {
    int p = tid & 63;
    const float* w = conv_w + (h * 64 + p) * K_CONV;
    float w0 = w[0], w1 = w[1], w2 = w[2], w3 = w[3];
    float cb = conv_b[h * 64 + p];
    for (int i = tid; i < CL * 64; i += 256) {
      int t = i >> 6;
      float a = cb + w0 * (float)rawx[t][p] + w1 * (float)rawx[t + 1][p]
                   + w2 * (float)rawx[t + 2][p] + w3 * (float)rawx[t + 3][p];
      lxT[p][t] = (__bf16)(a * sigmoidf_(a));
    }
  }
  {
    int n = tid & 31;
    const float* w = conv_w + (D_INNER + n) * K_CONV;
    float w0 = w[0], w1 = w[1], w2 = w[2], w3 = w[3];
    float cb = conv_b[D_INNER + n];
    for (int i = tid; i < CL * 32; i += 256) {
      int t = i >> 5;
      float a = cb + w0 * (float)rawB[t][n] + w1 * (float)rawB[t + 1][n]
                   + w2 * (float)rawB[t + 2][n] + w3 * (float)rawB[t + 3][n];
      float v = a * sigmoidf_(a);
      float wt = ldt[t] * __expf(A * (cs63 - lcs[t]));
      lBT[n][t] = (__bf16)(v * wt);
    }
  }
  __syncthreads();
  f32x4 acc[2];
  acc[0] = (f32x4){0.f,0.f,0.f,0.f}; acc[1] = (f32x4){0.f,0.f,0.f,0.f};
  #pragma unroll
  for (int kb = 0; kb < 2; kb++) {
    bf16x8 af = *(const bf16x8*)(&lxT[wave * 16 + l16][kb * 32 + q * 8]);
    #pragma unroll
    for (int j = 0; j < 2; j++) {
      bf16x8 bf = *(const bf16x8*)(&lBT[l16 + 16 * j][kb * 32 + q * 8]);
      acc[j] = __builtin_amdgcn_mfma_f32_16x16x32_bf16(af, bf, acc[j], 0, 0, 0);
    }
  }
  float* dst = Slocal + (size_t)blk * 2048;
  #pragma unroll
  for (int j = 0; j < 2; j++) {
    int n = l16 + 16 * j;
    #pragma unroll
    for (int rr = 0; rr < 4; rr++) {
      int p = wave * 16 + q * 4 + rr;
      dst[p * 32 + n] = acc[j][rr];
    }
  }
  if (tid == 0) dAprod[blk] = __expf(A * cs63);
}

// ssd_out: inline chunk-start scan over read-only Slocal (no combine kernel)
__global__ __launch_bounds__(256) void ssd_out_kernel(
    const __bf16* __restrict__ zxbf, const float* __restrict__ conv_w,
    const float* __restrict__ conv_b, const float* __restrict__ dt_bias,
    const float* __restrict__ A_log, const float* __restrict__ Dp,
    const float* __restrict__ Slocal, const float* __restrict__ dAprod,
    __bf16* __restrict__ y) {
  int blk = blockIdx.x;
  int c = blk % NC;
  int h = (blk / NC) % H_HEADS;
  int b = blk / (NC * H_HEADS);
  int tid = threadIdx.x;
  int lane = tid & 63, wave = tid >> 6;
  int q = lane >> 4, l16 = lane & 15;
  int t0 = c * CL;
  float A = -__expf(A_log[h]);
  float D = Dp[h];
  __shared__ __bf16 rawbuf[2 * 68 * 64];
  __shared__ __bf16 lxT[64][PSTR];
  __shared__ __bf16 lB[64][32];
  __shared__ __bf16 lC[64][32];
  __shared__ __bf16 lS[64][32];
  __shared__ float ldt[64], lcs[64];
  __shared__ float pr[NC];
  __bf16* rawx = rawbuf;
  __bf16* rawBC = rawbuf + 68 * 64;
  for (int i = tid; i < 68 * 8; i += 256) {
    int r = i >> 3, c0 = (i & 7) * 8;
    int gr = t0 - 3 + r;
    bf16x8 vx, vbc;
    #pragma unroll
    for (int k = 0; k < 8; k++) { vx[k] = (__bf16)0.f; vbc[k] = (__bf16)0.f; }
    if (gr >= 0) {
      const __bf16* rowp = zxbf + ((size_t)(b * SEQ + gr)) * D_IN_PROJ;
      vx  = *(const bf16x8*)(rowp + D_INNER + h * 64 + c0);
      vbc = *(const bf16x8*)(rowp + 2 * D_INNER + c0);
    }
    *(bf16x8*)(rawx + r * 64 + c0)  = vx;
    *(bf16x8*)(rawBC + r * 64 + c0) = vbc;
  }
  if (tid < NC) pr[tid] = dAprod[(blk - c) + tid];
  wave0_dt_cumsum(zxbf, dt_bias, b, h, t0, tid, ldt, lcs);
  __syncthreads();
  {
    int p = tid & 63;
    const float* w = conv_w + (h * 64 + p) * K_CONV;
    float w0 = w[0], w1 = w[1], w2 = w[2], w3 = w[3];
    float cb = conv_b[h * 64 + p];
    for (int i = tid; i < CL * 64; i += 256) {
      int t = i >> 6;
      float a = cb + w0 * (float)rawx[t * 64 + p] + w1 * (float)rawx[(t + 1) * 64 + p]
                   + w2 * (float)rawx[(t + 2) * 64 + p] + w3 * (float)rawx[(t + 3) * 64 + p];
      lxT[p][t] = (__bf16)(a * sigmoidf_(a));
    }
  }
  {
    int col = tid & 63;
    const float* w = conv_w + (D_INNER + col) * K_CONV;
    float w0 = w[0], w1 = w[1], w2 = w[2], w3 = w[3];
    float cb = conv_b[D_INNER + col];
    for (int i = tid; i < CL * 64; i += 256) {
      int t = i >> 6;
      float a = cb + w0 * (float)rawBC[t * 64 + col] + w1 * (float)rawBC[(t + 1) * 64 + col]
                   + w2 * (float)rawBC[(t + 2) * 64 + col] + w3 * (float)rawBC[(t + 3) * 64 + col];
      float v = a * sigmoidf_(a);
      if (col < 32) lB[t][col] = (__bf16)v; else lC[t][col - 32] = (__bf16)v;
    }
  }
  // inline chunk-start scan: Sstart_c = scan over Slocal chunks j<c
  {
    int p = tid >> 2, n0 = (tid & 3) * 8;
    const float* sl = Slocal + (size_t)(blk - c) * 2048 + p * 32 + n0;
    float st[8] = {};
    for (int j = 0; j < c; j++) {
      f32x4 a = *(const f32x4*)(sl + (size_t)j * 2048);
      f32x4 bq = *(const f32x4*)(sl + (size_t)j * 2048 + 4);
      float prj = pr[j];
      #pragma unroll
      for (int k = 0; k < 4; k++) { st[k] = prj * st[k] + a[k]; st[4 + k] = prj * st[4 + k] + bq[k]; }
    }
    #pragma unroll
    for (int k = 0; k < 8; k++) lS[p][n0 + k] = (__bf16)st[k];
  }
  __syncthreads();
  bf16x8 afC = *(const bf16x8*)(&lC[wave * 16 + l16][q * 8]);
  f32x4 accG[4], accI[4], accY[4];
  #pragma unroll
  for (int j = 0; j < 4; j++) {
    accG[j] = (f32x4){0.f,0.f,0.f,0.f};
    accI[j] = (f32x4){0.f,0.f,0.f,0.f};
    accY[j] = (f32x4){0.f,0.f,0.f,0.f};
  }
  #pragma unroll
  for (int j = 0; j < 4; j++) {
    bf16x8 bf = *(const bf16x8*)(&lB[l16 + 16 * j][q * 8]);
    accG[j] = __builtin_amdgcn_mfma_f32_16x16x32_bf16(afC, bf, accG[j], 0, 0, 0);
  }
  #pragma unroll
  for (int j = 0; j < 4; j++) {
    bf16x8 bf = *(const bf16x8*)(&lS[l16 + 16 * j][q * 8]);
    accI[j] = __builtin_amdgcn_mfma_f32_16x16x32_bf16(afC, bf, accI[j], 0, 0, 0);
  }
  __bf16* pP = rawbuf + wave * 16 * PSTR;   // wave-private slab over dead raw buffer
  #pragma unroll
  for (int j = 0; j < 4; j++) {
    int s = l16 + 16 * j;
    float css = lcs[s], dts = ldt[s];
    #pragma unroll
    for (int rr = 0; rr < 4; rr++) {
      int tl = q * 4 + rr;
      int t = wave * 16 + tl;
      float val = accG[j][rr] * __expf(A * (lcs[t] - css)) * dts;
      if (s == t) val += D;
      if (s > t) val = 0.f;
      pP[tl * PSTR + s] = (__bf16)val;
    }
  }
  #pragma unroll
  for (int kb = 0; kb < 2; kb++) {
    bf16x8 afP = *(const bf16x8*)(pP + l16 * PSTR + kb * 32 + q * 8);
    #pragma unroll
    for (int j = 0; j < 4; j++) {
      bf16x8 bf = *(const bf16x8*)(&lxT[l16 + 16 * j][kb * 32 + q * 8]);
      accY[j] = __builtin_amdgcn_mfma_f32_16x16x32_bf16(afP, bf, accY[j], 0, 0, 0);
    }
  }
  #pragma unroll
  for (int rr = 0; rr < 4; rr++) {
    int t = wave * 16 + q * 4 + rr;
    float cumt = __expf(A * lcs[t]);
    __bf16* yrow = y + ((size_t)(b * SEQ + t0 + t)) * D_INNER + h * 64;
    #pragma unroll
    for (int j = 0; j < 4; j++) {
      int p = l16 + 16 * j;
      yrow[p] = (__bf16)(accY[j][rr] + cumt * accI[j][rr]);
    }
  }
}

// ------- ybf = bf16( rmsnorm(y * silu(z)) * gnorm_w ), vectorized bf16x4 -------
__global__ void gate_norm_kernel(const __bf16* __restrict__ zxbf, const float* __restrict__ gw,
                                 const __bf16* __restrict__ y, __bf16* __restrict__ ybf) {
  int tok = blockIdx.x;
  int tid = threadIdx.x;
  bf16x4 vz = *(const bf16x4*)(zxbf + (size_t)tok * D_IN_PROJ + tid * 4);
  bf16x4 vy = *(const bf16x4*)(y + (size_t)tok * D_INNER + tid * 4);
  f32x4  wv = *(const f32x4*)(gw + tid * 4);
  float g[4];
  float ss = 0.f;
  #pragma unroll
  for (int i = 0; i < 4; i++) {
    float z = (float)vz[i];
    float gi = (float)vy[i] * z * sigmoidf_(z);
    g[i] = gi;
    ss += gi * gi;
  }
  #pragma unroll
  for (int o = 32; o >= 1; o >>= 1) ss += __shfl_xor(ss, o);
  __shared__ float red[4];
  if ((tid & 63) == 0) red[tid >> 6] = ss;
  __syncthreads();
  float tot = red[0] + red[1] + red[2] + red[3];
  float sc = rsqrtf(tot * (1.f / D_INNER) + EPS);
  bf16x4 o;
  #pragma unroll
  for (int i = 0; i < 4; i++) o[i] = (__bf16)(g[i] * sc * wv[i]);
  *(bf16x4*)(ybf + (size_t)tok * D_INNER + tid * 4) = o;
}

extern "C" void kernel_launch(void* const* d_in, const int* in_sizes, int n_in,
                              void* d_out, int out_size, void* d_ws, size_t ws_size,
                              hipStream_t stream) {
  const int*   tok     = (const int*)  d_in[0];
  const float* emb     = (const float*)d_in[1];
  const float* norm_w  = (const float*)d_in[2];
  const float* W_in    = (const float*)d_in[3];
  const float* b_in    = (const float*)d_in[4];
  const float* conv_w  = (const float*)d_in[5];
  const float* conv_b  = (const float*)d_in[6];
  const float* dt_bias = (const float*)d_in[7];
  const float* A_log   = (const float*)d_in[8];
  const float* D_par   = (const float*)d_in[9];
  const float* gnorm_w = (const float*)d_in[10];
  const float* W_out   = (const float*)d_in[11];
  const float* b_out   = (const float*)d_in[12];
  const float* head_w  = (const float*)d_in[13];
  const float* head_b  = (const float*)d_in[14];
  float* out = (float*)d_out;

  char* p = (char*)d_ws;
  auto alloc = [&](size_t bytes) { void* r = (void*)p; p += (bytes + 255) & ~(size_t)255; return r; };
  float*  h      = (float*) alloc((size_t)NTOK * D_MODEL * 4);
  float*  slocal = (float*) alloc((size_t)BATCH * H_HEADS * NC * P_HEAD * N_STATE * 4);
  float*  daprod = (float*) alloc((size_t)BATCH * H_HEADS * NC * 4);
  __bf16* y      = (__bf16*)alloc((size_t)NTOK * D_INNER * 2);
  __bf16* zxbf   = (__bf16*)alloc((size_t)NTOK * D_IN_PROJ * 2);
  __bf16* ubf    = (__bf16*)alloc((size_t)NTOK * D_MODEL * 2);
  __bf16* ybf    = (__bf16*)alloc((size_t)NTOK * D_INNER * 2);
  __bf16* hbf    = (__bf16*)alloc((size_t)NTOK * D_MODEL * 2);
  __bf16* WtIn   = (__bf16*)alloc((size_t)LAYERS * NPAD_IN * D_MODEL * 2);
  __bf16* WtOut  = (__bf16*)alloc((size_t)LAYERS * D_MODEL * D_INNER * 2);
  __bf16* WtHead = (__bf16*)alloc((size_t)NPAD_HEAD * D_MODEL * 2);

  transpose_cast_kernel<<<dim3(NPAD_IN / 32, D_MODEL / 32, LAYERS), 256, 0, stream>>>(
      W_in, WtIn, D_MODEL, D_IN_PROJ, NPAD_IN);
  transpose_cast_kernel<<<dim3(D_MODEL / 32, D_INNER / 32, LAYERS), 256, 0, stream>>>(
      W_out, WtOut, D_INNER, D_MODEL, D_MODEL);
  transpose_cast_kernel<<<dim3(NPAD_HEAD / 32, D_MODEL / 32, 1), 256, 0, stream>>>(
      head_w, WtHead, D_MODEL, VOCAB, NPAD_HEAD);

  for (int l = 0; l < LAYERS; l++) {
    rmsnorm512_kernel<<<NTOK, 256, 0, stream>>>(
        h, norm_w + (size_t)l * D_MODEL, ubf,
        (l == 0) ? tok : nullptr, (l == 0) ? emb : nullptr, h);

    gemm_bf16_128<<<dim3(NPAD_IN / 128, NTOK / 128), 256, 0, stream>>>(
        ubf, WtIn + (size_t)l * NPAD_IN * D_MODEL, b_in + (size_t)l * D_IN_PROJ,
        zxbf, D_MODEL, D_IN_PROJ, D_IN_PROJ);

    ssd_local_kernel<<<BATCH * H_HEADS * NC, 256, 0, stream>>>(
        zxbf, conv_w + (size_t)l * CONV_DIM * K_CONV, conv_b + (size_t)l * CONV_DIM,
        dt_bias + (size_t)l * H_HEADS, A_log + (size_t)l * H_HEADS, slocal, daprod);
    ssd_out_kernel<<<BATCH * H_HEADS * NC, 256, 0, stream>>>(
        zxbf, conv_w + (size_t)l * CONV_DIM * K_CONV, conv_b + (size_t)l * CONV_DIM,
        dt_bias + (size_t)l * H_HEADS, A_log + (size_t)l * H_HEADS,
        D_par + (size_t)l * H_HEADS, slocal, daprod, y);

    gate_norm_kernel<<<NTOK, 256, 0, stream>>>(zxbf, gnorm_w + (size_t)l * D_INNER, y, ybf);

    gemm_bf16_kernel<<<dim3(D_MODEL / TN, NTOK / TM), 256, 0, stream>>>(
        ybf, WtOut + (size_t)l * D_MODEL * D_INNER, b_out + (size_t)l * D_MODEL, h, h,
        (l == LAYERS - 1) ? hbf : nullptr, D_INNER, D_MODEL, D_MODEL);
  }

  gemm_bf16_kernel<<<dim3(NPAD_HEAD / TN, NTOK / TM), 256, 0, stream>>>(
      hbf, WtHead, head_b, nullptr, out, nullptr, D_MODEL, VOCAB, VOCAB);
}

// Round 17
// 494.329 us; speedup vs baseline: 1.0055x; 1.0055x over previous
//
#include <hip/hip_runtime.h>
#include <hip/hip_bf16.h>

#define VOCAB     64
#define D_MODEL   512
#define N_STATE   32
#define H_HEADS   16
#define LAYERS    4
#define D_INNER   1024
#define P_HEAD    64
#define CONV_DIM  1088
#define K_CONV    4
#define D_IN_PROJ 2128
#define NPAD_IN   2176          // 17*128
#define NPAD_HEAD 128
#define BATCH     4
#define SEQ       1024
#define NTOK      (BATCH*SEQ)
#define EPS       1e-5f
#define CL        64            // scan chunk length
#define NC        (SEQ/CL)      // 16 chunks
#define PSTR      80            // padded t-stride (bf16) for transposed LDS tiles

typedef __bf16 bf16x8 __attribute__((ext_vector_type(8)));
typedef float  f32x4  __attribute__((ext_vector_type(4)));

__device__ __forceinline__ float sigmoidf_(float x) { return 1.f / (1.f + __expf(-x)); }
__device__ __forceinline__ float softplusf_(float x) { return (x > 20.f) ? x : log1pf(__expf(x)); }

// ---------------- rmsnorm over D_MODEL=512, bf16 out; layer0 fuses embed ----------------
__global__ void rmsnorm512_kernel(const float* __restrict__ x, const float* __restrict__ w,
                                  __bf16* __restrict__ out,
                                  const int* __restrict__ tok, const float* __restrict__ emb,
                                  float* __restrict__ hout) {
  int tokid = blockIdx.x;
  int tid = threadIdx.x;
  float v0, v1;
  if (tok) {
    const float* er = emb + (size_t)tok[tokid] * D_MODEL;
    v0 = er[tid]; v1 = er[tid + 256];
    float* hr = hout + (size_t)tokid * D_MODEL;
    hr[tid] = v0; hr[tid + 256] = v1;
  } else {
    const float* xr = x + (size_t)tokid * D_MODEL;
    v0 = xr[tid]; v1 = xr[tid + 256];
  }
  float ss = v0 * v0 + v1 * v1;
  #pragma unroll
  for (int o = 32; o >= 1; o >>= 1) ss += __shfl_xor(ss, o);
  __shared__ float red[4];
  if ((tid & 63) == 0) red[tid >> 6] = ss;
  __syncthreads();
  float tot = red[0] + red[1] + red[2] + red[3];
  float sc = rsqrtf(tot * (1.f / D_MODEL) + EPS);
  out[(size_t)tokid * D_MODEL + tid]       = (__bf16)(v0 * sc * w[tid]);
  out[(size_t)tokid * D_MODEL + tid + 256] = (__bf16)(v1 * sc * w[tid + 256]);
}

// ---- batched weight transpose+cast: W[z][K][N] f32 -> Wt[z][Npad][K] bf16 ----
__global__ void transpose_cast_kernel(const float* __restrict__ W, __bf16* __restrict__ Wt,
                                      int K, int N, int Npad) {
  W  += (size_t)blockIdx.z * K * N;
  Wt += (size_t)blockIdx.z * Npad * K;
  __shared__ float T[32][33];
  int n0 = blockIdx.x * 32, k0 = blockIdx.y * 32;
  int tx = threadIdx.x & 31, ty = threadIdx.x >> 5;  // ty 0..7
  #pragma unroll
  for (int i = 0; i < 4; i++) {
    int n = n0 + tx;
    T[ty + i * 8][tx] = (n < N) ? W[(size_t)(k0 + ty + i * 8) * N + n] : 0.f;
  }
  __syncthreads();
  #pragma unroll
  for (int i = 0; i < 4; i++)
    Wt[(size_t)(n0 + ty + i * 8) * K + k0 + tx] = (__bf16)T[tx][ty + i * 8];
}

// ---------------- bf16 MFMA GEMM, 64x128 tile (out_proj / head) ----------------
#define TM 64
#define TN 128
#define TK 64
__global__ __launch_bounds__(256) void gemm_bf16_kernel(
    const __bf16* __restrict__ A, const __bf16* __restrict__ Bt,
    const float* __restrict__ bias, const float* __restrict__ res,
    float* __restrict__ C, __bf16* __restrict__ Cbf, int K, int N, int ldc) {
  __shared__ __bf16 As[TM * TK];
  __shared__ __bf16 Bs[TN * TK];
  int tid = threadIdx.x;
  int lane = tid & 63, wave = tid >> 6;
  int wm = wave >> 1, wn = wave & 1;
  int q = lane >> 4, l16 = lane & 15;
  size_t row0 = (size_t)blockIdx.y * TM;
  int col0 = blockIdx.x * TN;
  const __bf16* Ab = A + row0 * K;
  const __bf16* Bb = Bt + (size_t)col0 * K;

  bf16x8 pa[2], pb[4];
  #pragma unroll
  for (int r = 0; r < 2; r++) {
    int lin = r * 256 + tid;
    pa[r] = *(const bf16x8*)(Ab + (size_t)(lin >> 3) * K + (lin & 7) * 8);
  }
  #pragma unroll
  for (int r = 0; r < 4; r++) {
    int lin = r * 256 + tid;
    pb[r] = *(const bf16x8*)(Bb + (size_t)(lin >> 3) * K + (lin & 7) * 8);
  }

  f32x4 acc[2][4];
  #pragma unroll
  for (int i = 0; i < 2; i++)
    #pragma unroll
    for (int j = 0; j < 4; j++) acc[i][j] = (f32x4){0.f, 0.f, 0.f, 0.f};

  for (int k0 = 0; k0 < K; k0 += TK) {
    #pragma unroll
    for (int r = 0; r < 2; r++) { int lin = r * 256 + tid; *(bf16x8*)(As + lin * 8) = pa[r]; }
    #pragma unroll
    for (int r = 0; r < 4; r++) { int lin = r * 256 + tid; *(bf16x8*)(Bs + lin * 8) = pb[r]; }
    __syncthreads();
    int kn = k0 + TK;
    if (kn < K) {
      #pragma unroll
      for (int r = 0; r < 2; r++) {
        int lin = r * 256 + tid;
        pa[r] = *(const bf16x8*)(Ab + (size_t)(lin >> 3) * K + kn + (lin & 7) * 8);
      }
      #pragma unroll
      for (int r = 0; r < 4; r++) {
        int lin = r * 256 + tid;
        pb[r] = *(const bf16x8*)(Bb + (size_t)(lin >> 3) * K + kn + (lin & 7) * 8);
      }
    }
    #pragma unroll
    for (int ks = 0; ks < 2; ks++) {
      bf16x8 af[2], bfv[4];
      #pragma unroll
      for (int i = 0; i < 2; i++)
        af[i] = *(const bf16x8*)(As + (wm * 32 + i * 16 + l16) * TK + ks * 32 + q * 8);
      #pragma unroll
      for (int j = 0; j < 4; j++)
        bfv[j] = *(const bf16x8*)(Bs + (wn * 64 + j * 16 + l16) * TK + ks * 32 + q * 8);
      #pragma unroll
      for (int i = 0; i < 2; i++)
        #pragma unroll
        for (int j = 0; j < 4; j++)
          acc[i][j] = __builtin_amdgcn_mfma_f32_16x16x32_bf16(af[i], bfv[j], acc[i][j], 0, 0, 0);
    }
    __syncthreads();
  }

  #pragma unroll
  for (int i = 0; i < 2; i++) {
    size_t mrow = row0 + wm * 32 + i * 16 + q * 4;
    #pragma unroll
    for (int j = 0; j < 4; j++) {
      int col = col0 + wn * 64 + j * 16 + l16;
      if (col < N) {
        float bv = bias ? bias[col] : 0.f;
        #pragma unroll
        for (int rr = 0; rr < 4; rr++) {
          size_t off = (mrow + rr) * (size_t)ldc + col;
          float v = acc[i][j][rr] + bv;
          if (res) v += res[off];
          if (C)   C[off] = v;
          if (Cbf) Cbf[off] = (__bf16)v;
        }
      }
    }
  }
}

// ---------------- bf16 MFMA GEMM, 128x128 tile (in_proj) ----------------
__global__ __launch_bounds__(256) void gemm_bf16_128(
    const __bf16* __restrict__ A, const __bf16* __restrict__ Bt,
    const float* __restrict__ bias, __bf16* __restrict__ Cbf,
    int K, int N, int ldc) {
  __shared__ __bf16 As[128 * TK];
  __shared__ __bf16 Bs[128 * TK];
  int tid = threadIdx.x;
  int lane = tid & 63, wave = tid >> 6;
  int wm = wave >> 1, wn = wave & 1;
  int q = lane >> 4, l16 = lane & 15;
  size_t row0 = (size_t)blockIdx.y * 128;
  int col0 = blockIdx.x * 128;
  const __bf16* Ab = A + row0 * K;
  const __bf16* Bb = Bt + (size_t)col0 * K;

  bf16x8 pa[4], pb[4];
  #pragma unroll
  for (int r = 0; r < 4; r++) {
    int lin = r * 256 + tid;
    pa[r] = *(const bf16x8*)(Ab + (size_t)(lin >> 3) * K + (lin & 7) * 8);
    pb[r] = *(const bf16x8*)(Bb + (size_t)(lin >> 3) * K + (lin & 7) * 8);
  }

  f32x4 acc[4][4];
  #pragma unroll
  for (int i = 0; i < 4; i++)
    #pragma unroll
    for (int j = 0; j < 4; j++) acc[i][j] = (f32x4){0.f, 0.f, 0.f, 0.f};

  for (int k0 = 0; k0 < K; k0 += TK) {
    #pragma unroll
    for (int r = 0; r < 4; r++) {
      int lin = r * 256 + tid;
      *(bf16x8*)(As + lin * 8) = pa[r];
      *(bf16x8*)(Bs + lin * 8) = pb[r];
    }
    __syncthreads();
    int kn = k0 + TK;
    if (kn < K) {
      #pragma unroll
      for (int r = 0; r < 4; r++) {
        int lin = r * 256 + tid;
        pa[r] = *(const bf16x8*)(Ab + (size_t)(lin >> 3) * K + kn + (lin & 7) * 8);
        pb[r] = *(const bf16x8*)(Bb + (size_t)(lin >> 3) * K + kn + (lin & 7) * 8);
      }
    }
    #pragma unroll
    for (int ks = 0; ks < 2; ks++) {
      bf16x8 af[4], bfv[4];
      #pragma unroll
      for (int i = 0; i < 4; i++)
        af[i] = *(const bf16x8*)(As + (wm * 64 + i * 16 + l16) * TK + ks * 32 + q * 8);
      #pragma unroll
      for (int j = 0; j < 4; j++)
        bfv[j] = *(const bf16x8*)(Bs + (wn * 64 + j * 16 + l16) * TK + ks * 32 + q * 8);
      #pragma unroll
      for (int i = 0; i < 4; i++)
        #pragma unroll
        for (int j = 0; j < 4; j++)
          acc[i][j] = __builtin_amdgcn_mfma_f32_16x16x32_bf16(af[i], bfv[j], acc[i][j], 0, 0, 0);
    }
    __syncthreads();
  }

  #pragma unroll
  for (int i = 0; i < 4; i++) {
    size_t mrow = row0 + wm * 64 + i * 16 + q * 4;
    #pragma unroll
    for (int j = 0; j < 4; j++) {
      int col = col0 + wn * 64 + j * 16 + l16;
      if (col < N) {
        float bv = bias[col];
        #pragma unroll
        for (int rr = 0; rr < 4; rr++)
          Cbf[(mrow + rr) * (size_t)ldc + col] = (__bf16)(acc[i][j][rr] + bv);
      }
    }
  }
}

// ================= MFMA chunked SSD =================
// zxbf row: [z 0..1024 | x 1024..2048 | B 2048..2080 | C 2080..2112 | dt 2112..2128]
__device__ __forceinline__ void wave0_dt_cumsum(
    const __bf16* __restrict__ zxbf, const float* __restrict__ dt_bias,
    int b, int h, int t0, int tid, float* ldt, float* lcs) {
  if (tid < 64) {
    float dv = (float)zxbf[((size_t)(b * SEQ + t0 + tid)) * D_IN_PROJ + 2 * D_INNER + 2 * N_STATE + h]
               + dt_bias[h];
    float dtv = softplusf_(dv);
    float cs = dtv;
    #pragma unroll
    for (int off = 1; off < 64; off <<= 1) {
      float o = __shfl_up(cs, off);
      if (tid >= off) cs += o;
    }
    ldt[tid] = dtv;
    lcs[tid] = cs;
  }
}

__global__ __launch_bounds__(256) void ssd_local_kernel(
    const __bf16* __restrict__ zxbf, const float* __restrict__ conv_w,
    const float* __restrict__ conv_b, const float* __restrict__ dt_bias,
    const float* __restrict__ A_log,
    float* __restrict__ Slocal, float* __restrict__ dAprod) {
  int blk = blockIdx.x;
  int c = blk % NC;
  int h = (blk / NC) % H_HEADS;
  int b = blk / (NC * H_HEADS);
  int tid = threadIdx.x;
  int lane = tid & 63, wave = tid >> 6;
  int q = lane >> 4, l16 = lane & 15;
  int t0 = c * CL;
  float A = -__expf(A_log[h]);
  __shared__ __bf16 rawx[68][64];
  __shared__ __bf16 rawB[68][32];
  __shared__ __bf16 lxT[64][PSTR];
  __shared__ __bf16 lBT[32][PSTR];
  __shared__ float ldt[64], lcs[64];
  for (int i = tid; i < 68 * 8; i += 256) {
    int r = i >> 3, c0 = (i & 7) * 8;
    int gr = t0 - 3 + r;
    bf16x8 v;
    #pragma unroll
    for (int k = 0; k < 8; k++) v[k] = (__bf16)0.f;
    if (gr >= 0)
      v = *(const bf16x8*)(zxbf + ((size_t)(b * SEQ + gr)) * D_IN_PROJ + D_INNER + h * 64 + c0);
    *(bf16x8*)(&rawx[r][c0]) = v;
  }
  for (int i = tid; i < 68 * 4; i += 256) {
    int r = i >> 2, c0 = (i & 3) * 8;
    int gr = t0 - 3 + r;
    bf16x8 v;
    #pragma unroll
    for (int k = 0; k < 8; k++) v[k] = (__bf16)0.f;
    if (gr >= 0)
      v = *(const bf16x8*)(zxbf + ((size_t)(b * SEQ + gr)) * D_IN_PROJ + 2 * D_INNER + c0);
    *(bf16x8*)(&rawB[r][c0]) = v;
  }
  wave0_dt_cumsum(zxbf, dt_bias, b, h, t0, tid, ldt, lcs);
  __syncthreads();
  float cs63 = lcs[63];
  {
    int p = tid & 63;
    const float* w = conv_w + (h * 64 + p) * K_CONV;
    float w0 = w[0], w1 = w[1], w2 = w[2], w3 = w[3];
    float cb = conv_b[h * 64 + p];
    for (int i = tid; i < CL * 64; i += 256) {
      int t = i >> 6;
      float a = cb + w0 * (float)rawx[t][p] + w1 * (float)rawx[t + 1][p]
                   + w2 * (float)rawx[t + 2][p] + w3 * (float)rawx[t + 3][p];
      lxT[p][t] = (__bf16)(a * sigmoidf_(a));
    }
  }
  {
    int n = tid & 31;
    const float* w = conv_w + (D_INNER + n) * K_CONV;
    float w0 = w[0], w1 = w[1], w2 = w[2], w3 = w[3];
    float cb = conv_b[D_INNER + n];
    for (int i = tid; i < CL * 32; i += 256) {
      int t = i >> 5;
      float a = cb + w0 * (float)rawB[t][n] + w1 * (float)rawB[t + 1][n]
                   + w2 * (float)rawB[t + 2][n] + w3 * (float)rawB[t + 3][n];
      float v = a * sigmoidf_(a);
      float wt = ldt[t] * __expf(A * (cs63 - lcs[t]));
      lBT[n][t] = (__bf16)(v * wt);
    }
  }
  __syncthreads();
  f32x4 acc[2];
  acc[0] = (f32x4){0.f,0.f,0.f,0.f}; acc[1] = (f32x4){0.f,0.f,0.f,0.f};
  #pragma unroll
  for (int kb = 0; kb < 2; kb++) {
    bf16x8 af = *(const bf16x8*)(&lxT[wave * 16 + l16][kb * 32 + q * 8]);
    #pragma unroll
    for (int j = 0; j < 2; j++) {
      bf16x8 bf = *(const bf16x8*)(&lBT[l16 + 16 * j][kb * 32 + q * 8]);
      acc[j] = __builtin_amdgcn_mfma_f32_16x16x32_bf16(af, bf, acc[j], 0, 0, 0);
    }
  }
  float* dst = Slocal + (size_t)blk * 2048;
  #pragma unroll
  for (int j = 0; j < 2; j++) {
    int n = l16 + 16 * j;
    #pragma unroll
    for (int rr = 0; rr < 4; rr++) {
      int p = wave * 16 + q * 4 + rr;
      dst[p * 32 + n] = acc[j][rr];
    }
  }
  if (tid == 0) dAprod[blk] = __expf(A * cs63);
}

// ssd_out: inline chunk-start scan over read-only Slocal (no combine kernel)
__global__ __launch_bounds__(256) void ssd_out_kernel(
    const __bf16* __restrict__ zxbf, const float* __restrict__ conv_w,
    const float* __restrict__ conv_b, const float* __restrict__ dt_bias,
    const float* __restrict__ A_log, const float* __restrict__ Dp,
    const float* __restrict__ Slocal, const float* __restrict__ dAprod,
    __bf16* __restrict__ y) {
  int blk = blockIdx.x;
  int c = blk % NC;
  int h = (blk / NC) % H_HEADS;
  int b = blk / (NC * H_HEADS);
  int tid = threadIdx.x;
  int lane = tid & 63, wave = tid >> 6;
  int q = lane >> 4, l16 = lane & 15;
  int t0 = c * CL;
  float A = -__expf(A_log[h]);
  float D = Dp[h];
  __shared__ __bf16 rawbuf[2 * 68 * 64];
  __shared__ __bf16 lxT[64][PSTR];
  __shared__ __bf16 lB[64][32];
  __shared__ __bf16 lC[64][32];
  __shared__ __bf16 lS[64][32];
  __shared__ float ldt[64], lcs[64];
  __shared__ float pr[NC];
  __bf16* rawx = rawbuf;
  __bf16* rawBC = rawbuf + 68 * 64;
  for (int i = tid; i < 68 * 8; i += 256) {
    int r = i >> 3, c0 = (i & 7) * 8;
    int gr = t0 - 3 + r;
    bf16x8 vx, vbc;
    #pragma unroll
    for (int k = 0; k < 8; k++) { vx[k] = (__bf16)0.f; vbc[k] = (__bf16)0.f; }
    if (gr >= 0) {
      const __bf16* rowp = zxbf + ((size_t)(b * SEQ + gr)) * D_IN_PROJ;
      vx  = *(const bf16x8*)(rowp + D_INNER + h * 64 + c0);
      vbc = *(const bf16x8*)(rowp + 2 * D_INNER + c0);
    }
    *(bf16x8*)(rawx + r * 64 + c0)  = vx;
    *(bf16x8*)(rawBC + r * 64 + c0) = vbc;
  }
  if (tid < NC) pr[tid] = dAprod[(blk - c) + tid];
  wave0_dt_cumsum(zxbf, dt_bias, b, h, t0, tid, ldt, lcs);
  __syncthreads();
  {
    int p = tid & 63;
    const float* w = conv_w + (h * 64 + p) * K_CONV;
    float w0 = w[0], w1 = w[1], w2 = w[2], w3 = w[3];
    float cb = conv_b[h * 64 + p];
    for (int i = tid; i < CL * 64; i += 256) {
      int t = i >> 6;
      float a = cb + w0 * (float)rawx[t * 64 + p] + w1 * (float)rawx[(t + 1) * 64 + p]
                   + w2 * (float)rawx[(t + 2) * 64 + p] + w3 * (float)rawx[(t + 3) * 64 + p];
      lxT[p][t] = (__bf16)(a * sigmoidf_(a));
    }
  }
  {
    int col = tid & 63;
    const float* w = conv_w + (D_INNER + col) * K_CONV;
    float w0 = w[0], w1 = w[1], w2 = w[2], w3 = w[3];
    float cb = conv_b[D_INNER + col];
    for (int i = tid; i < CL * 64; i += 256) {
      int t = i >> 6;
      float a = cb + w0 * (float)rawBC[t * 64 + col] + w1 * (float)rawBC[(t + 1) * 64 + col]
                   + w2 * (float)rawBC[(t + 2) * 64 + col] + w3 * (float)rawBC[(t + 3) * 64 + col];
      float v = a * sigmoidf_(a);
      if (col < 32) lB[t][col] = (__bf16)v; else lC[t][col - 32] = (__bf16)v;
    }
  }
  // inline chunk-start scan: Sstart_c = scan over Slocal chunks j<c
  {
    int p = tid >> 2, n0 = (tid & 3) * 8;
    const float* sl = Slocal + (size_t)(blk - c) * 2048 + p * 32 + n0;
    float st[8] = {};
    for (int j = 0; j < c; j++) {
      f32x4 a = *(const f32x4*)(sl + (size_t)j * 2048);
      f32x4 bq = *(const f32x4*)(sl + (size_t)j * 2048 + 4);
      float prj = pr[j];
      #pragma unroll
      for (int k = 0; k < 4; k++) { st[k] = prj * st[k] + a[k]; st[4 + k] = prj * st[4 + k] + bq[k]; }
    }
    #pragma unroll
    for (int k = 0; k < 8; k++) lS[p][n0 + k] = (__bf16)st[k];
  }
  __syncthreads();
  bf16x8 afC = *(const bf16x8*)(&lC[wave * 16 + l16][q * 8]);
  f32x4 accG[4], accI[4], accY[4];
  #pragma unroll
  for (int j = 0; j < 4; j++) {
    accG[j] = (f32x4){0.f,0.f,0.f,0.f};
    accI[j] = (f32x4){0.f,0.f,0.f,0.f};
    accY[j] = (f32x4){0.f,0.f,0.f,0.f};
  }
  #pragma unroll
  for (int j = 0; j < 4; j++) {
    bf16x8 bf = *(const bf16x8*)(&lB[l16 + 16 * j][q * 8]);
    accG[j] = __builtin_amdgcn_mfma_f32_16x16x32_bf16(afC, bf, accG[j], 0, 0, 0);
  }
  #pragma unroll
  for (int j = 0; j < 4; j++) {
    bf16x8 bf = *(const bf16x8*)(&lS[l16 + 16 * j][q * 8]);
    accI[j] = __builtin_amdgcn_mfma_f32_16x16x32_bf16(afC, bf, accI[j], 0, 0, 0);
  }
  __bf16* pP = rawbuf + wave * 16 * PSTR;   // wave-private slab over dead raw buffer
  #pragma unroll
  for (int j = 0; j < 4; j++) {
    int s = l16 + 16 * j;
    float css = lcs[s], dts = ldt[s];
    #pragma unroll
    for (int rr = 0; rr < 4; rr++) {
      int tl = q * 4 + rr;
      int t = wave * 16 + tl;
      float val = accG[j][rr] * __expf(A * (lcs[t] - css)) * dts;
      if (s == t) val += D;
      if (s > t) val = 0.f;
      pP[tl * PSTR + s] = (__bf16)val;
    }
  }
  #pragma unroll
  for (int kb = 0; kb < 2; kb++) {
    bf16x8 afP = *(const bf16x8*)(pP + l16 * PSTR + kb * 32 + q * 8);
    #pragma unroll
    for (int j = 0; j < 4; j++) {
      bf16x8 bf = *(const bf16x8*)(&lxT[l16 + 16 * j][kb * 32 + q * 8]);
      accY[j] = __builtin_amdgcn_mfma_f32_16x16x32_bf16(afP, bf, accY[j], 0, 0, 0);
    }
  }
  #pragma unroll
  for (int rr = 0; rr < 4; rr++) {
    int t = wave * 16 + q * 4 + rr;
    float cumt = __expf(A * lcs[t]);
    __bf16* yrow = y + ((size_t)(b * SEQ + t0 + t)) * D_INNER + h * 64;
    #pragma unroll
    for (int j = 0; j < 4; j++) {
      int p = l16 + 16 * j;
      yrow[p] = (__bf16)(accY[j][rr] + cumt * accI[j][rr]);
    }
  }
}

// ---------------- ybf = bf16( rmsnorm(y * silu(z)) * gnorm_w ) ----------------
__global__ void gate_norm_kernel(const __bf16* __restrict__ zxbf, const float* __restrict__ gw,
                                 const __bf16* __restrict__ y, __bf16* __restrict__ ybf) {
  int tok = blockIdx.x;
  int tid = threadIdx.x;
  const __bf16* zr = zxbf + (size_t)tok * D_IN_PROJ;
  const __bf16* yr = y + (size_t)tok * D_INNER;
  float v[4];
  float ss = 0.f;
  #pragma unroll
  for (int i = 0; i < 4; i++) {
    int d = tid + i * 256;
    float z = (float)zr[d];
    float g = (float)yr[d] * z * sigmoidf_(z);
    v[i] = g;
    ss += g * g;
  }
  #pragma unroll
  for (int o = 32; o >= 1; o >>= 1) ss += __shfl_xor(ss, o);
  __shared__ float red[4];
  if ((tid & 63) == 0) red[tid >> 6] = ss;
  __syncthreads();
  float tot = red[0] + red[1] + red[2] + red[3];
  float sc = rsqrtf(tot * (1.f / D_INNER) + EPS);
  #pragma unroll
  for (int i = 0; i < 4; i++) {
    int d = tid + i * 256;
    ybf[(size_t)tok * D_INNER + d] = (__bf16)(v[i] * sc * gw[d]);
  }
}

extern "C" void kernel_launch(void* const* d_in, const int* in_sizes, int n_in,
                              void* d_out, int out_size, void* d_ws, size_t ws_size,
                              hipStream_t stream) {
  const int*   tok     = (const int*)  d_in[0];
  const float* emb     = (const float*)d_in[1];
  const float* norm_w  = (const float*)d_in[2];
  const float* W_in    = (const float*)d_in[3];
  const float* b_in    = (const float*)d_in[4];
  const float* conv_w  = (const float*)d_in[5];
  const float* conv_b  = (const float*)d_in[6];
  const float* dt_bias = (const float*)d_in[7];
  const float* A_log   = (const float*)d_in[8];
  const float* D_par   = (const float*)d_in[9];
  const float* gnorm_w = (const float*)d_in[10];
  const float* W_out   = (const float*)d_in[11];
  const float* b_out   = (const float*)d_in[12];
  const float* head_w  = (const float*)d_in[13];
  const float* head_b  = (const float*)d_in[14];
  float* out = (float*)d_out;

  char* p = (char*)d_ws;
  auto alloc = [&](size_t bytes) { void* r = (void*)p; p += (bytes + 255) & ~(size_t)255; return r; };
  float*  h      = (float*) alloc((size_t)NTOK * D_MODEL * 4);
  float*  slocal = (float*) alloc((size_t)BATCH * H_HEADS * NC * P_HEAD * N_STATE * 4);
  float*  daprod = (float*) alloc((size_t)BATCH * H_HEADS * NC * 4);
  __bf16* y      = (__bf16*)alloc((size_t)NTOK * D_INNER * 2);
  __bf16* zxbf   = (__bf16*)alloc((size_t)NTOK * D_IN_PROJ * 2);
  __bf16* ubf    = (__bf16*)alloc((size_t)NTOK * D_MODEL * 2);
  __bf16* ybf    = (__bf16*)alloc((size_t)NTOK * D_INNER * 2);
  __bf16* hbf    = (__bf16*)alloc((size_t)NTOK * D_MODEL * 2);
  __bf16* WtIn   = (__bf16*)alloc((size_t)LAYERS * NPAD_IN * D_MODEL * 2);
  __bf16* WtOut  = (__bf16*)alloc((size_t)LAYERS * D_MODEL * D_INNER * 2);
  __bf16* WtHead = (__bf16*)alloc((size_t)NPAD_HEAD * D_MODEL * 2);

  transpose_cast_kernel<<<dim3(NPAD_IN / 32, D_MODEL / 32, LAYERS), 256, 0, stream>>>(
      W_in, WtIn, D_MODEL, D_IN_PROJ, NPAD_IN);
  transpose_cast_kernel<<<dim3(D_MODEL / 32, D_INNER / 32, LAYERS), 256, 0, stream>>>(
      W_out, WtOut, D_INNER, D_MODEL, D_MODEL);
  transpose_cast_kernel<<<dim3(NPAD_HEAD / 32, D_MODEL / 32, 1), 256, 0, stream>>>(
      head_w, WtHead, D_MODEL, VOCAB, NPAD_HEAD);

  for (int l = 0; l < LAYERS; l++) {
    rmsnorm512_kernel<<<NTOK, 256, 0, stream>>>(
        h, norm_w + (size_t)l * D_MODEL, ubf,
        (l == 0) ? tok : nullptr, (l == 0) ? emb : nullptr, h);

    gemm_bf16_128<<<dim3(NPAD_IN / 128, NTOK / 128), 256, 0, stream>>>(
        ubf, WtIn + (size_t)l * NPAD_IN * D_MODEL, b_in + (size_t)l * D_IN_PROJ,
        zxbf, D_MODEL, D_IN_PROJ, D_IN_PROJ);

    ssd_local_kernel<<<BATCH * H_HEADS * NC, 256, 0, stream>>>(
        zxbf, conv_w + (size_t)l * CONV_DIM * K_CONV, conv_b + (size_t)l * CONV_DIM,
        dt_bias + (size_t)l * H_HEADS, A_log + (size_t)l * H_HEADS, slocal, daprod);
    ssd_out_kernel<<<BATCH * H_HEADS * NC, 256, 0, stream>>>(
        zxbf, conv_w + (size_t)l * CONV_DIM * K_CONV, conv_b + (size_t)l * CONV_DIM,
        dt_bias + (size_t)l * H_HEADS, A_log + (size_t)l * H_HEADS,
        D_par + (size_t)l * H_HEADS, slocal, daprod, y);

    gate_norm_kernel<<<NTOK, 256, 0, stream>>>(zxbf, gnorm_w + (size_t)l * D_INNER, y, ybf);

    gemm_bf16_kernel<<<dim3(D_MODEL / TN, NTOK / TM), 256, 0, stream>>>(
        ybf, WtOut + (size_t)l * D_MODEL * D_INNER, b_out + (size_t)l * D_MODEL, h, h,
        (l == LAYERS - 1) ? hbf : nullptr, D_INNER, D_MODEL, D_MODEL);
  }

  gemm_bf16_kernel<<<dim3(NPAD_HEAD / TN, NTOK / TM), 256, 0, stream>>>(
      hbf, WtHead, head_b, nullptr, out, nullptr, D_MODEL, VOCAB, VOCAB);
}